// Round 4
// baseline (687.304 us; speedup 1.0000x reference)
//
#include <hip/hip_runtime.h>
#include <hip/hip_bf16.h>
#include <stdint.h>

#define HIDDEN 1024
#define FFN    4096
#define NROWS  8192   // 4*2048
#define TOPK_K 32
#define NCAND  40
#define MU     5e-4f
#define KC     384    // OpenBLAS SGEMM_DEFAULT_Q (Haswell/Zen)

#define BM 128
#define BN 128
#define BK 32

typedef __attribute__((ext_vector_type(8))) short bf16x8;
typedef __attribute__((ext_vector_type(4))) float f32x4;
typedef unsigned long long u64;

// ---------------------------------------------------------------- helpers
__device__ __forceinline__ unsigned short f2bf_rne(float f) {
  unsigned u = __float_as_uint(f);
  unsigned r = (u + 0x7FFFu + ((u >> 16) & 1u)) >> 16;
  return (unsigned short)r;
}
__device__ __forceinline__ float bf2f(unsigned short b) {
  return __uint_as_float((unsigned)b << 16);
}

__device__ __forceinline__ void async_copy16(const void* g, void* l) {
  __builtin_amdgcn_global_load_lds((void __attribute__((address_space(1)))*)(g),
                                   (void __attribute__((address_space(3)))*)(l),
                                   16, 0, 0);
}

// ------------------------------------------------- split fp32 -> bf16 hi/lo
__global__ void split_fp32_to_bf16x2(const float* __restrict__ in,
                                     unsigned short* __restrict__ hi,
                                     unsigned short* __restrict__ lo,
                                     int n4) {
  int i = blockIdx.x * blockDim.x + threadIdx.x;
  int stride = gridDim.x * blockDim.x;
  for (; i < n4; i += stride) {
    float4 v = reinterpret_cast<const float4*>(in)[i];
    ushort4 h, l;
    h.x = f2bf_rne(v.x); l.x = f2bf_rne(v.x - bf2f(h.x));
    h.y = f2bf_rne(v.y); l.y = f2bf_rne(v.y - bf2f(h.y));
    h.z = f2bf_rne(v.z); l.z = f2bf_rne(v.z - bf2f(h.z));
    h.w = f2bf_rne(v.w); l.w = f2bf_rne(v.w - bf2f(h.w));
    reinterpret_cast<ushort4*>(hi)[i] = h;
    reinterpret_cast<ushort4*>(lo)[i] = l;
  }
}

// ------------------------------------------------- transpose W2 [1024][4096] -> [4096][1024]
__global__ void transpose_w2(const float* __restrict__ in, float* __restrict__ out) {
  __shared__ float tile[32][33];
  int bx = blockIdx.x * 32;              // FFN
  int by = blockIdx.y * 32;              // HIDDEN
  int tx = threadIdx.x & 31, ty = threadIdx.x >> 5;   // 32 x 8
#pragma unroll
  for (int r = 0; r < 32; r += 8)
    tile[ty + r][tx] = in[(size_t)(by + ty + r) * FFN + bx + tx];
  __syncthreads();
#pragma unroll
  for (int r = 0; r < 32; r += 8)
    out[(size_t)(bx + ty + r) * HIDDEN + by + tx] = tile[tx][ty + r];
}

// ------------------------------------------------- GEMM1: h = x @ W1^T + b1
// split-bf16, 3 products: xh*wh + xh*wl + xl*wh  (~2.3e-6 abs error)
__global__ __launch_bounds__(256)
void gemm_split3(const unsigned short* __restrict__ xh,
                 const unsigned short* __restrict__ xl,
                 const unsigned short* __restrict__ wh,
                 const unsigned short* __restrict__ wl,
                 const float* __restrict__ b1,
                 float* __restrict__ hout) {
  __shared__ __align__(16) unsigned short smem[4 * BM * BK];
  unsigned short* sAh = smem;
  unsigned short* sAl = smem + BM * BK;
  unsigned short* sBh = smem + 2 * BM * BK;
  unsigned short* sBl = smem + 3 * BM * BK;

  const int tid = threadIdx.x;
  const int rowBase = blockIdx.x * BM;
  const int colBase = blockIdx.y * BN;

  const int wid = tid >> 6, lane = tid & 63;
  const int wr = (wid >> 1) * 64;       // wave row offset in tile
  const int wc = (wid & 1) * 64;        // wave col offset in tile
  const int lr = lane & 15;
  const int k0 = (lane >> 4) * 8;

  const int r0 = tid >> 2;              // 0..63
  const int r1 = r0 + 64;               // 64..127
  const int kk = (tid & 3) * 8;
  const int off0 = r0 * BK + kk;
  const int off1 = r1 * BK + kk;

  const size_t gA0 = (size_t)(rowBase + r0) * HIDDEN + kk;
  const size_t gA1 = (size_t)(rowBase + r1) * HIDDEN + kk;
  const size_t gB0 = (size_t)(colBase + r0) * HIDDEN + kk;
  const size_t gB1 = (size_t)(colBase + r1) * HIDDEN + kk;

  f32x4 acc[4][4];
  const f32x4 zero4 = {0.f, 0.f, 0.f, 0.f};
#pragma unroll
  for (int m = 0; m < 4; ++m)
#pragma unroll
    for (int n = 0; n < 4; ++n) acc[m][n] = zero4;

  for (int kb = 0; kb < HIDDEN; kb += BK) {
    async_copy16(xh + gA0 + kb, sAh + off0);
    async_copy16(xh + gA1 + kb, sAh + off1);
    async_copy16(xl + gA0 + kb, sAl + off0);
    async_copy16(xl + gA1 + kb, sAl + off1);
    async_copy16(wh + gB0 + kb, sBh + off0);
    async_copy16(wh + gB1 + kb, sBh + off1);
    async_copy16(wl + gB0 + kb, sBl + off0);
    async_copy16(wl + gB1 + kb, sBl + off1);
    __syncthreads();

    bf16x8 ah[4], al[4], bh[4], bl[4];
#pragma unroll
    for (int m = 0; m < 4; ++m) {
      int r = (wr + m * 16 + lr) * BK + k0;
      ah[m] = *(const bf16x8*)(sAh + r);
      al[m] = *(const bf16x8*)(sAl + r);
    }
#pragma unroll
    for (int n = 0; n < 4; ++n) {
      int c = (wc + n * 16 + lr) * BK + k0;
      bh[n] = *(const bf16x8*)(sBh + c);
      bl[n] = *(const bf16x8*)(sBl + c);
    }
#pragma unroll
    for (int m = 0; m < 4; ++m)
#pragma unroll
      for (int n = 0; n < 4; ++n) {
        acc[m][n] = __builtin_amdgcn_mfma_f32_16x16x32_bf16(ah[m], bh[n], acc[m][n], 0, 0, 0);
        acc[m][n] = __builtin_amdgcn_mfma_f32_16x16x32_bf16(ah[m], bl[n], acc[m][n], 0, 0, 0);
        acc[m][n] = __builtin_amdgcn_mfma_f32_16x16x32_bf16(al[m], bh[n], acc[m][n], 0, 0, 0);
      }
    __syncthreads();
  }

  // C/D layout (verified m89/m91): col = lane&15, row = (lane>>4)*4 + reg
  const int ccol = lane & 15;
  const int crow = (lane >> 4) * 4;
#pragma unroll
  for (int n = 0; n < 4; ++n) {
    int col = colBase + wc + n * 16 + ccol;
    float bias = b1[col];
#pragma unroll
    for (int m = 0; m < 4; ++m) {
      int rowb = rowBase + wr + m * 16 + crow;
#pragma unroll
      for (int j = 0; j < 4; ++j)
        hout[(size_t)(rowb + j) * FFN + col] = acc[m][n][j] + bias;
    }
  }
}

// ------------------------------------------------- per-row top-40 + OpenBLAS-emulating refine
// Candidates from the approximate h (error ~2.3e-6 << MU band). Boundary
// near-ties re-evaluated with an emulation of OpenBLAS sgemm's per-element
// rounding: kc-panelled (KC=384) ascending-k fp32 FMA chains, panel partials
// merged with fp32 adds (C += panel), then one fp32 add of b1. Ranking by
// (fp32 |h| bits desc, idx asc) replicates top_k on the reference's values.
__global__ __launch_bounds__(256)
void topk_kernel(const float* __restrict__ h,
                 const float* __restrict__ x,
                 const float* __restrict__ W1,
                 const float* __restrict__ b1,
                 int* __restrict__ oidx,
                 float* __restrict__ ocoef) {
  const int row = blockIdx.x;
  const int tid = threadIdx.x;
  const float* hr = h + (size_t)row * FFN;

  float v[16];
  u64 key[16];
#pragma unroll
  for (int j = 0; j < 16; ++j) {
    float xv = hr[j * 256 + tid];
    v[j] = xv;
    unsigned ab = __float_as_uint(fabsf(xv));
    unsigned idx = (unsigned)(j * 256 + tid);
    key[j] = ((u64)ab << 32) | (u64)(0xFFFFFFFFu - idx);
  }

  __shared__ u64 swk[4];
  __shared__ float sval[NCAND];
  __shared__ int   sidx[NCAND];
  __shared__ int   sS, sB;
  __shared__ float sv32[NCAND];
  __shared__ int   fidx[TOPK_K];
  __shared__ float fcoef[TOPK_K];

  for (int it = 0; it < NCAND; ++it) {
    u64 best = key[0];
#pragma unroll
    for (int j = 1; j < 16; ++j) best = key[j] > best ? key[j] : best;
#pragma unroll
    for (int off = 32; off > 0; off >>= 1) {
      u64 o = __shfl_down(best, (unsigned)off);
      if (o > best) best = o;
    }
    if ((tid & 63) == 0) swk[tid >> 6] = best;
    __syncthreads();
    u64 b = swk[0];
    b = swk[1] > b ? swk[1] : b;
    b = swk[2] > b ? swk[2] : b;
    b = swk[3] > b ? swk[3] : b;
#pragma unroll
    for (int j = 0; j < 16; ++j) {
      if (key[j] == b) {
        sval[it] = v[j];
        sidx[it] = (int)(0xFFFFFFFFu - (unsigned)(b & 0xFFFFFFFFull));
        key[j] = 0;
      }
    }
    __syncthreads();
  }

  // classify: sure-in prefix (> t+MU) vs boundary band [t-MU, t+MU]
  if (tid == 0) {
    float t = fabsf(sval[TOPK_K - 1]);
    int s = 0;
    while (s < TOPK_K - 1 && fabsf(sval[s]) > t + MU) ++s;
    int e = s;
    while (e < NCAND && fabsf(sval[e]) >= t - MU) ++e;
    sS = s;
    sB = e - s;       // >= 1 always (slot 31 is in the band)
  }
  __syncthreads();
  const int s = sS, nb = sB;

  // OpenBLAS-sgemm rounding emulation for boundary candidates
  // (one thread per candidate; chains are inherently serial)
  if (nb > 1 && tid < nb) {
    const int fi = sidx[s + tid];
    const float* xr = x + (size_t)row * HIDDEN;
    const float* w1r = W1 + (size_t)fi * HIDDEN;
    float p0 = 0.0f, p1 = 0.0f, p2 = 0.0f;
    for (int k2 = 0; k2 < KC; ++k2)
      p0 = __builtin_fmaf(xr[k2], w1r[k2], p0);
    for (int k2 = KC; k2 < 2 * KC; ++k2)
      p1 = __builtin_fmaf(xr[k2], w1r[k2], p1);
    for (int k2 = 2 * KC; k2 < HIDDEN; ++k2)
      p2 = __builtin_fmaf(xr[k2], w1r[k2], p2);
    float acc = __fadd_rn(__fadd_rn(p0, p1), p2);   // C += panel merges
    sv32[tid] = __fadd_rn(acc, b1[fi]);
  }
  __syncthreads();

  if (tid == 0) {
    // default: slots 0..31 with coefficients from the approximate values
    for (int k2 = 0; k2 < TOPK_K; ++k2) {
      fidx[k2] = sidx[k2];
      float hv = sval[k2];
      fcoef[k2] = __fmul_rn(__fmul_rn(hv, hv), hv);
    }
    if (nb > 1) {
      // choose remaining (32 - s) among boundary by (fp32 |h| bits desc, idx asc)
      int need = TOPK_K - s;
      u64 used = 0;
      for (int n = 0; n < need; ++n) {
        int bestc = -1;
        u64 bestk = 0;
        for (int c = 0; c < nb; ++c) {
          if (used & (1ull << c)) continue;
          unsigned ab = __float_as_uint(fabsf(sv32[c]));
          u64 kk2 = ((u64)ab << 32) | (u64)(0xFFFFFFFFu - (unsigned)sidx[s + c]);
          if (bestc < 0 || kk2 > bestk) { bestk = kk2; bestc = c; }
        }
        used |= 1ull << bestc;
        float hv = sv32[bestc];
        fidx[s + n] = sidx[s + bestc];
        fcoef[s + n] = __fmul_rn(__fmul_rn(hv, hv), hv);
      }
    }
    // sort selected by index ascending: matches the reference's dense
    // ascending-f accumulation order in GEMM2
    for (int a2 = 1; a2 < TOPK_K; ++a2) {
      int ia = fidx[a2]; float ca = fcoef[a2];
      int bq = a2 - 1;
      while (bq >= 0 && fidx[bq] > ia) {
        fidx[bq + 1] = fidx[bq]; fcoef[bq + 1] = fcoef[bq]; --bq;
      }
      fidx[bq + 1] = ia; fcoef[bq + 1] = ca;
    }
  }
  __syncthreads();
  if (tid < TOPK_K) {
    oidx[(size_t)row * TOPK_K + tid] = fidx[tid];
    ocoef[(size_t)row * TOPK_K + tid] = fcoef[tid];
  }
}

// ------------------------------------------------- GEMM2: sparse gather
// indices pre-sorted ascending; accumulate from 0, add b2 last (ref order)
__global__ __launch_bounds__(256)
void scatter_kernel(const int* __restrict__ oidx,
                    const float* __restrict__ ocoef,
                    const float* __restrict__ w2t,
                    const float* __restrict__ b2,
                    float* __restrict__ out) {
  const int row = blockIdx.x;
  const int tid = threadIdx.x;
  __shared__ int sIdx[TOPK_K];
  __shared__ float sCf[TOPK_K];
  if (tid < TOPK_K) {
    sIdx[tid] = oidx[(size_t)row * TOPK_K + tid];
    sCf[tid] = ocoef[(size_t)row * TOPK_K + tid];
  }
  __syncthreads();

  float4 acc = {0.f, 0.f, 0.f, 0.f};
  for (int j = 0; j < TOPK_K; ++j) {
    const float4 w = reinterpret_cast<const float4*>(w2t + (size_t)sIdx[j] * HIDDEN)[tid];
    float c = sCf[j];
    acc.x = __builtin_fmaf(c, w.x, acc.x);
    acc.y = __builtin_fmaf(c, w.y, acc.y);
    acc.z = __builtin_fmaf(c, w.z, acc.z);
    acc.w = __builtin_fmaf(c, w.w, acc.w);
  }
  const float4 bb = reinterpret_cast<const float4*>(b2)[tid];
  acc.x += bb.x; acc.y += bb.y; acc.z += bb.z; acc.w += bb.w;
  reinterpret_cast<float4*>(out)[(size_t)row * (HIDDEN / 4) + tid] = acc;
}

// ------------------------------------------------- launch
extern "C" void kernel_launch(void* const* d_in, const int* in_sizes, int n_in,
                              void* d_out, int out_size, void* d_ws, size_t ws_size,
                              hipStream_t stream) {
  (void)in_sizes; (void)n_in; (void)out_size; (void)ws_size;
  const float* x  = (const float*)d_in[0];
  const float* W1 = (const float*)d_in[1];
  const float* b1 = (const float*)d_in[2];
  const float* W2 = (const float*)d_in[3];
  const float* b2 = (const float*)d_in[4];
  float* out = (float*)d_out;

  // workspace layout (~203 MB total)
  unsigned short* xh = (unsigned short*)d_ws;                     // 16.78 MB
  unsigned short* xl = xh + (size_t)NROWS * HIDDEN;               // 16.78 MB
  unsigned short* wh = xl + (size_t)NROWS * HIDDEN;               //  8.39 MB
  unsigned short* wl = wh + (size_t)FFN * HIDDEN;                 //  8.39 MB
  float* w2t  = (float*)(wl + (size_t)FFN * HIDDEN);              // 16.78 MB
  float* hbuf = w2t + (size_t)FFN * HIDDEN;                       // 134.2 MB
  int*   tidx = (int*)(hbuf + (size_t)NROWS * FFN);               //  1.05 MB
  float* tcoef = (float*)(tidx + (size_t)NROWS * TOPK_K);         //  1.05 MB

  split_fp32_to_bf16x2<<<2048, 256, 0, stream>>>(x, xh, xl, NROWS * HIDDEN / 4);
  split_fp32_to_bf16x2<<<1024, 256, 0, stream>>>(W1, wh, wl, FFN * HIDDEN / 4);
  transpose_w2<<<dim3(FFN / 32, HIDDEN / 32), 256, 0, stream>>>(W2, w2t);
  gemm_split3<<<dim3(NROWS / BM, FFN / BN), 256, 0, stream>>>(xh, xl, wh, wl, b1, hbuf);
  topk_kernel<<<NROWS, 256, 0, stream>>>(hbuf, x, W1, b1, tidx, tcoef);
  scatter_kernel<<<NROWS, 256, 0, stream>>>(tidx, tcoef, w2t, b2, out);
}